// Round 6
// baseline (613.341 us; speedup 1.0000x reference)
//
#include <hip/hip_runtime.h>
#include <hip/hip_bf16.h>
#include <stdint.h>

#define NTOK 4096   // B*T = 2*2048
#define CD   1024
#define HD   4096
#define NE   8

typedef __attribute__((ext_vector_type(8))) short bf16x8;
typedef __attribute__((ext_vector_type(4))) float f32x4;
typedef __attribute__((ext_vector_type(4))) unsigned short us4;

#define BARR() asm volatile("s_barrier" ::: "memory")
#define VMW4() asm volatile("s_waitcnt vmcnt(4)" ::: "memory")
#define VMW0() asm volatile("s_waitcnt vmcnt(0)" ::: "memory")

__device__ __forceinline__ unsigned short f2bf(float f){
  __hip_bfloat16 h = __float2bfloat16(f);
  return *reinterpret_cast<unsigned short*>(&h);
}

// ---------------- router: logits (fp64 accum), softmax, top-2, renorm; x -> bf16 ----------------
__global__ __launch_bounds__(256) void router_kernel(
    const float* __restrict__ x, const float* __restrict__ rw,
    unsigned short* __restrict__ x_bf, int* __restrict__ top_i,
    float* __restrict__ top_w, int* __restrict__ counts){
  __shared__ float rw_lds[NE*CD];
  int tid = threadIdx.x;
  for (int i = tid; i < NE*CD/4; i += 256)
    ((float4*)rw_lds)[i] = ((const float4*)rw)[i];
  __syncthreads();
  int l = tid & 63, w = tid >> 6;
  int n = blockIdx.x*4 + w;

  float4 xv[4];
  #pragma unroll
  for (int j = 0; j < 4; ++j)
    xv[j] = ((const float4*)(x + (size_t)n*CD))[l + j*64];

  #pragma unroll
  for (int j = 0; j < 4; ++j){
    us4 o; o.x = f2bf(xv[j].x); o.y = f2bf(xv[j].y); o.z = f2bf(xv[j].z); o.w = f2bf(xv[j].w);
    *(us4*)(x_bf + (size_t)n*CD + l*4 + j*256) = o;
  }

  double le[NE];
  #pragma unroll
  for (int e = 0; e < NE; ++e){
    double p = 0.0;
    #pragma unroll
    for (int j = 0; j < 4; ++j){
      float4 rv = ((const float4*)(rw_lds + e*CD))[l + j*64];
      p += (double)xv[j].x*rv.x + (double)xv[j].y*rv.y + (double)xv[j].z*rv.z + (double)xv[j].w*rv.w;
    }
    #pragma unroll
    for (int d = 32; d >= 1; d >>= 1) p += __shfl_xor(p, d);
    le[e] = p;
  }
  if (l == 0){
    double m = le[0];
    #pragma unroll
    for (int e = 1; e < NE; ++e) m = le[e] > m ? le[e] : m;
    double pe[NE];
    #pragma unroll
    for (int e = 0; e < NE; ++e) pe[e] = exp(le[e]-m);
    int i0 = 0;
    #pragma unroll
    for (int e = 1; e < NE; ++e) if (pe[e] > pe[i0]) i0 = e;     // strict > : ties -> lower idx (matches lax.top_k)
    int i1 = (i0 == 0) ? 1 : 0;
    #pragma unroll
    for (int e = 0; e < NE; ++e){ if (e == i0) continue; if (pe[e] > pe[i1]) i1 = e; }
    double w0 = pe[i0], w1v = pe[i1], wsum = w0 + w1v;
    top_i[2*n] = i0; top_i[2*n+1] = i1;
    top_w[2*n] = (float)(w0/wsum); top_w[2*n+1] = (float)(w1v/wsum);
    atomicAdd(&counts[i0], 1); atomicAdd(&counts[i1], 1);
  }
}

// ---------------- tiny scan: 8-entry exclusive prefix ----------------
__global__ void scan_kernel(const int* __restrict__ counts, int* __restrict__ offsets, int* __restrict__ cursor){
  if (threadIdx.x == 0){
    int s = 0;
    for (int e = 0; e < NE; ++e){ offsets[e] = s; cursor[e] = s; s += counts[e]; }
  }
}

// ---------------- scatter tokens into expert-grouped lists ----------------
__global__ __launch_bounds__(256) void scatter_kernel(
    const int* __restrict__ top_i, const float* __restrict__ top_w,
    int* __restrict__ cursor, int* __restrict__ g_tok, float* __restrict__ g_w){
  int n = blockIdx.x*256 + threadIdx.x;
  #pragma unroll
  for (int k = 0; k < 2; ++k){
    int e = top_i[2*n+k];
    int pos = atomicAdd(&cursor[e], 1);
    g_tok[pos] = n;
    g_w[pos] = top_w[2*n+k];
  }
}

// ---------------- weight transpose + fp32->bf16: in [R][S] -> out [S][R], per expert ----------------
template<int R, int S>
__global__ __launch_bounds__(256) void transpose_cvt(const float* __restrict__ in, unsigned short* __restrict__ outp){
  __shared__ float tile[64][65];
  int e = blockIdx.z;
  const float* ip = in + (size_t)e*R*S;
  unsigned short* op = outp + (size_t)e*R*S;
  int s0 = blockIdx.x*64, r0 = blockIdx.y*64;
  int tid = threadIdx.x;
  #pragma unroll
  for (int i = 0; i < 4; ++i){
    int lin = i*256 + tid;
    int rr = lin >> 4, c4 = lin & 15;
    float4 v = *(const float4*)(ip + (size_t)(r0+rr)*S + s0 + c4*4);
    tile[rr][c4*4+0] = v.x; tile[rr][c4*4+1] = v.y;
    tile[rr][c4*4+2] = v.z; tile[rr][c4*4+3] = v.w;
  }
  __syncthreads();
  #pragma unroll
  for (int i = 0; i < 4; ++i){
    int lin = i*256 + tid;
    int ss = lin >> 4, rq = lin & 15;
    us4 o;
    o.x = f2bf(tile[rq*4+0][ss]);
    o.y = f2bf(tile[rq*4+1][ss]);
    o.z = f2bf(tile[rq*4+2][ss]);
    o.w = f2bf(tile[rq*4+3][ss]);
    *(us4*)(op + (size_t)(s0+ss)*R + r0 + rq*4) = o;
  }
}

// ---------------- grouped GEMM, 8-phase 256x256 template (T2+T3+T4+T5) ----------------
// BK=64, 8 waves (2Mx4N, per-wave 128x64 = 8x4 frags). KLEN=1024 = 16 K-tiles = 8 iters.
// LDS 128KB: buf b at b*65536; A at 0 (halves mh*16384), B at 32768 (halves nh*16384).
// Half = 128 wave-aligned rows x 64K x 2B = 16KB = 2 global_load_lds_dwordx4 per thread-set.
// Per iter (tiles t0=2i,t1=2i+1), phase p: {ds_read subtile; stage 1 half; BAR; 16 MFMA(setprio); BAR}
//   p0: rd A[h0]B[h0]@buf0, stage buf1.Ah1(t1)     p4: rd A[h0]B[h0]@buf1, stage buf0.Ah1(t0+2)
//   p1: rd B[h1]@buf0,      stage buf1.Bh1(t1)     p5: rd B[h1]@buf1,      stage buf0.Bh1(t0+2)
//   p2: rd A[h1]@buf0,      stage buf0.Ah0(t0+2)   p6: rd A[h1]@buf1,      stage buf1.Ah0(t1+2)
//   p3:                     stage buf0.Bh0(t0+2),  p7:                     stage buf1.Bh0(t1+2),
//       vmcnt(4)                                       vmcnt(4)
// Each stage targets a quarter dead since the previous phase; vmcnt(4) (=2 phases x 2 loads)
// guarantees all older stages landed before the barrier releases readers. Last iter: skip
// p2..p7 stages, vmcnt(0) at p3. Raw s_barrier (no vmcnt(0) drain) is the whole point (T4).
// EPI 0: h = gelu(x @ w1t^T) bf16.  EPI 1: out[token] += w * (h @ w2t^T), fp32 atomics.
template<int EPI, int SPLITK>
__global__ __launch_bounds__(512, 2) void gemm8ph(
    const unsigned short* __restrict__ A_src,
    const unsigned short* __restrict__ B_src,
    unsigned short* __restrict__ h_out,
    float* __restrict__ outp,
    const int* __restrict__ g_tok,
    const float* __restrict__ g_w,
    const int* __restrict__ counts,
    const int* __restrict__ offsets,
    int NDIM, int KSTRIDE){
  __shared__ alignas(128) char lds[131072];

  int z = blockIdx.z;
  int e  = z / SPLITK;
  int kz = z % SPLITK;
  int n_e = counts[e];
  int m0 = blockIdx.y*256;
  if (m0 >= n_e) return;
  int n0 = blockIdx.x*256;
  int g_base = offsets[e];
  int kstart = kz*1024;

  int tid = threadIdx.x, l = tid & 63, w = tid >> 6;   // 8 waves
  int wr = w >> 2, wc = w & 3;                         // wave tile: rows wr*128, cols wc*64
  int lrow = l & 15, q = l >> 4;

  // staging precompute. kinds: 0=A_h0 1=B_h0 2=A_h1 3=B_h1; j=0,1 insts per half.
  // halfrow r = j*64 + w*8 + (l>>3); LDS linear dst = region + j*8192 + w*1024 + l*16
  // source chunk pre-swizzled: c = (l&7) ^ (r&7)  ->  LDS(r,c) = SRC(r, c^(r&7))
  const unsigned short* sp[4][2];
  uint32_t sd[4][2];
  #pragma unroll
  for (int kind = 0; kind < 4; ++kind){
    #pragma unroll
    for (int j = 0; j < 2; ++j){
      int r = j*64 + w*8 + (l >> 3);
      int h = kind >> 1;
      int c = (l & 7) ^ (r & 7);
      if ((kind & 1) == 0){   // A: half h = rows {wr128 + h*64 .. +63}
        int trow = (r >> 6)*128 + h*64 + (r & 63);
        int rg = m0 + trow; if (rg > n_e-1) rg = n_e-1;   // clamp partial tile
        size_t arow = (EPI == 0) ? (size_t)g_tok[g_base + rg] : (size_t)(g_base + rg);
        sp[kind][j] = A_src + arow*(size_t)KSTRIDE + kstart + c*8;
        sd[kind][j] = h*16384u + (uint32_t)(j*8192 + w*1024 + l*16);
      } else {                // B: half h = rows {wc*64 + h*32 .. +31}
        int trow = (r >> 5)*64 + h*32 + (r & 31);
        sp[kind][j] = B_src + ((size_t)e*NDIM + n0 + trow)*(size_t)KSTRIDE + kstart + c*8;
        sd[kind][j] = 32768u + h*16384u + (uint32_t)(j*8192 + w*1024 + l*16);
      }
    }
  }

  auto STG = [&](int kind, int buf, int kt){
    #pragma unroll
    for (int j = 0; j < 2; ++j)
      __builtin_amdgcn_global_load_lds(
        (const __attribute__((address_space(1))) void*)(sp[kind][j] + kt*64),
        (__attribute__((address_space(3))) void*)&lds[sd[kind][j] + (uint32_t)buf*65536u], 16, 0, 0);
  };

  // fragment read offsets within half: byte = halfrow*128 + 16*(q ^ (lrow&7)); ks=1 -> ^64
  uint32_t aoff[2][4], boff[2][2];
  #pragma unroll
  for (int mh = 0; mh < 2; ++mh)
    #pragma unroll
    for (int mm = 0; mm < 4; ++mm)
      aoff[mh][mm] = mh*16384u + (uint32_t)((wr*64 + mm*16 + lrow)*128) + 16u*(q ^ (lrow & 7));
  #pragma unroll
  for (int nh = 0; nh < 2; ++nh)
    #pragma unroll
    for (int nn = 0; nn < 2; ++nn)
      boff[nh][nn] = 32768u + nh*16384u + (uint32_t)((wc*32 + nn*16 + lrow)*128) + 16u*(q ^ (lrow & 7));

  bf16x8 a[4][2], b[2][2][2];
  f32x4 acc[8][4] = {};

  auto RDA = [&](int mh, int buf){
    #pragma unroll
    for (int mm = 0; mm < 4; ++mm)
      #pragma unroll
      for (int ks = 0; ks < 2; ++ks)
        a[mm][ks] = *(const bf16x8*)&lds[(aoff[mh][mm] ^ (ks*64)) + (uint32_t)buf*65536u];
  };
  auto RDB = [&](int nh, int buf){
    #pragma unroll
    for (int nn = 0; nn < 2; ++nn)
      #pragma unroll
      for (int ks = 0; ks < 2; ++ks)
        b[nh][nn][ks] = *(const bf16x8*)&lds[(boff[nh][nn] ^ (ks*64)) + (uint32_t)buf*65536u];
  };
  auto MM = [&](int mh, int nh){
    __builtin_amdgcn_s_setprio(1);
    #pragma unroll
    for (int mm = 0; mm < 4; ++mm)
      #pragma unroll
      for (int nn = 0; nn < 2; ++nn)
        #pragma unroll
        for (int ks = 0; ks < 2; ++ks)
          acc[mh*4+mm][nh*2+nn] =
            __builtin_amdgcn_mfma_f32_16x16x32_bf16(a[mm][ks], b[nh][nn][ks], acc[mh*4+mm][nh*2+nn], 0, 0, 0);
    __builtin_amdgcn_s_setprio(0);
  };

  // prologue: tile0 -> buf0 (all 4 halves), tile1 -> buf1 (Ah0, Bh0)
  STG(0,0,0); STG(1,0,0); STG(2,0,0); STG(3,0,0);
  STG(0,1,1); STG(1,1,1);
  VMW4();              // tile0 fully landed (tile1 pair may fly)
  BARR();

  auto iter = [&](int i, bool last){
    int t1 = 2*i + 1;
    // p0
    RDA(0,0); RDB(0,0); STG(2,1,t1);
    BARR(); MM(0,0); BARR();
    // p1
    RDB(1,0); STG(3,1,t1);
    BARR(); MM(0,1); BARR();
    // p2
    RDA(1,0); if (!last) STG(0,0,t1+1);
    BARR(); MM(1,0); BARR();
    // p3
    if (!last){ STG(1,0,t1+1); VMW4(); } else { VMW0(); }
    BARR(); MM(1,1); BARR();
    // p4
    RDA(0,1); RDB(0,1); if (!last) STG(2,0,t1+1);
    BARR(); MM(0,0); BARR();
    // p5
    RDB(1,1); if (!last) STG(3,0,t1+1);
    BARR(); MM(0,1); BARR();
    // p6
    RDA(1,1); if (!last) STG(0,1,t1+2);
    BARR(); MM(1,0); BARR();
    // p7
    if (!last){ STG(1,1,t1+2); VMW4(); }
    BARR(); MM(1,1); BARR();
  };

  #pragma unroll 1
  for (int i = 0; i < 7; ++i) iter(i, false);
  iter(7, true);

  // C/D layout (verified m89): col = lane&15, row = (lane>>4)*4 + j
  if (EPI == 0){
    #pragma unroll
    for (int m = 0; m < 8; ++m){
      #pragma unroll
      for (int j = 0; j < 4; ++j){
        int r = m0 + wr*128 + m*16 + q*4 + j;
        if (r < n_e){
          unsigned short* hp = h_out + (size_t)(g_base + r)*NDIM + n0 + wc*64 + lrow;
          #pragma unroll
          for (int n = 0; n < 4; ++n){
            float v = acc[m][n][j];
            v = 0.5f*v*(1.0f + erff(v*0.70710678118654752f));   // exact GELU
            hp[n*16] = f2bf(v);
          }
        }
      }
    }
  } else {
    #pragma unroll
    for (int m = 0; m < 8; ++m){
      #pragma unroll
      for (int j = 0; j < 4; ++j){
        int r = m0 + wr*128 + m*16 + q*4 + j;
        if (r < n_e){
          int slot = g_base + r;
          int t = g_tok[slot];
          float wgt = g_w[slot];
          float* op = outp + (size_t)t*NDIM + n0 + wc*64 + lrow;
          #pragma unroll
          for (int n = 0; n < 4; ++n)
            atomicAdd(op + n*16, wgt*acc[m][n][j]);
        }
      }
    }
  }
}

extern "C" void kernel_launch(void* const* d_in, const int* in_sizes, int n_in,
                              void* d_out, int out_size, void* d_ws, size_t ws_size,
                              hipStream_t stream) {
  const float* x  = (const float*)d_in[0];
  const float* rw = (const float*)d_in[1];
  const float* w1 = (const float*)d_in[2];
  const float* w2 = (const float*)d_in[3];

  size_t off = 0;
  auto alloc = [&](size_t sz) -> char* {
    char* p = (char*)d_ws + off;
    off += (sz + 255) & ~(size_t)255;
    return p;
  };
  unsigned short* x_bf = (unsigned short*)alloc((size_t)NTOK*CD*2);   // 8.4 MB
  unsigned short* w1t  = (unsigned short*)alloc((size_t)NE*CD*HD*2);  // 67 MB  [E][H][C]
  unsigned short* w2t  = (unsigned short*)alloc((size_t)NE*CD*HD*2);  // 67 MB  [E][C][H]
  unsigned short* hbuf = (unsigned short*)alloc((size_t)NTOK*2*HD*2); // 67 MB  [slot][H]
  int*   top_i  = (int*)alloc(NTOK*2*4);
  float* top_w  = (float*)alloc(NTOK*2*4);
  int*   counts = (int*)alloc(64);
  int*   offs   = (int*)alloc(64);
  int*   cursor = (int*)alloc(64);
  int*   g_tok  = (int*)alloc(NTOK*2*4);
  float* g_w    = (float*)alloc(NTOK*2*4);
  (void)ws_size; (void)in_sizes; (void)n_in; (void)out_size;

  hipMemsetAsync(d_out, 0, (size_t)NTOK*CD*4, stream);
  hipMemsetAsync(counts, 0, 64, stream);

  router_kernel<<<dim3(NTOK/4), dim3(256), 0, stream>>>(x, rw, x_bf, top_i, top_w, counts);
  scan_kernel<<<dim3(1), dim3(64), 0, stream>>>(counts, offs, cursor);
  scatter_kernel<<<dim3(NTOK/256), dim3(256), 0, stream>>>(top_i, top_w, cursor, g_tok, g_w);

  transpose_cvt<CD, HD><<<dim3(HD/64, CD/64, NE), dim3(256), 0, stream>>>(w1, w1t);
  transpose_cvt<HD, CD><<<dim3(CD/64, HD/64, NE), dim3(256), 0, stream>>>(w2, w2t);

  // GEMM1: h = gelu(x @ w1t^T)   M=n_e, N=H (4096 -> 16 nblk), K=1024; ~576 useful blocks
  gemm8ph<0, 1><<<dim3(16, 16, NE), dim3(512), 0, stream>>>(
      x_bf, w1t, hbuf, (float*)nullptr, g_tok, g_w, counts, offs, HD, CD);
  // GEMM2: out += w * (h @ w2t^T)   M=n_e, N=C (1024 -> 4 nblk), K=4096 split-K x4; ~576 useful
  gemm8ph<1, 4><<<dim3(4, 16, NE*4), dim3(512), 0, stream>>>(
      hbuf, w2t, (unsigned short*)nullptr, (float*)d_out, g_tok, g_w, counts, offs, CD, HD);
}

// Round 7
// 612.899 us; speedup vs baseline: 1.0007x; 1.0007x over previous
//
#include <hip/hip_runtime.h>
#include <hip/hip_bf16.h>
#include <stdint.h>

#define NTOK 4096   // B*T = 2*2048
#define CD   1024
#define HD   4096
#define NE   8

typedef __attribute__((ext_vector_type(8))) short bf16x8;
typedef __attribute__((ext_vector_type(4))) float f32x4;
typedef __attribute__((ext_vector_type(4))) unsigned short us4;

#define BARR() asm volatile("s_barrier" ::: "memory")
#define VM0() asm volatile("s_waitcnt vmcnt(0)" ::: "memory")
#define VM2() asm volatile("s_waitcnt vmcnt(2)" ::: "memory")
#define VM4() asm volatile("s_waitcnt vmcnt(4)" ::: "memory")
#define VM6() asm volatile("s_waitcnt vmcnt(6)" ::: "memory")
#define VM8() asm volatile("s_waitcnt vmcnt(8)" ::: "memory")

__device__ __forceinline__ unsigned short f2bf(float f){
  __hip_bfloat16 h = __float2bfloat16(f);
  return *reinterpret_cast<unsigned short*>(&h);
}

// ---------------- router: logits (fp64 accum), softmax, top-2, renorm; x -> bf16 ----------------
__global__ __launch_bounds__(256) void router_kernel(
    const float* __restrict__ x, const float* __restrict__ rw,
    unsigned short* __restrict__ x_bf, int* __restrict__ top_i,
    float* __restrict__ top_w, int* __restrict__ counts){
  __shared__ float rw_lds[NE*CD];
  int tid = threadIdx.x;
  for (int i = tid; i < NE*CD/4; i += 256)
    ((float4*)rw_lds)[i] = ((const float4*)rw)[i];
  __syncthreads();
  int l = tid & 63, w = tid >> 6;
  int n = blockIdx.x*4 + w;

  float4 xv[4];
  #pragma unroll
  for (int j = 0; j < 4; ++j)
    xv[j] = ((const float4*)(x + (size_t)n*CD))[l + j*64];

  #pragma unroll
  for (int j = 0; j < 4; ++j){
    us4 o; o.x = f2bf(xv[j].x); o.y = f2bf(xv[j].y); o.z = f2bf(xv[j].z); o.w = f2bf(xv[j].w);
    *(us4*)(x_bf + (size_t)n*CD + l*4 + j*256) = o;
  }

  double le[NE];
  #pragma unroll
  for (int e = 0; e < NE; ++e){
    double p = 0.0;
    #pragma unroll
    for (int j = 0; j < 4; ++j){
      float4 rv = ((const float4*)(rw_lds + e*CD))[l + j*64];
      p += (double)xv[j].x*rv.x + (double)xv[j].y*rv.y + (double)xv[j].z*rv.z + (double)xv[j].w*rv.w;
    }
    #pragma unroll
    for (int d = 32; d >= 1; d >>= 1) p += __shfl_xor(p, d);
    le[e] = p;
  }
  if (l == 0){
    double m = le[0];
    #pragma unroll
    for (int e = 1; e < NE; ++e) m = le[e] > m ? le[e] : m;
    double pe[NE];
    #pragma unroll
    for (int e = 0; e < NE; ++e) pe[e] = exp(le[e]-m);
    int i0 = 0;
    #pragma unroll
    for (int e = 1; e < NE; ++e) if (pe[e] > pe[i0]) i0 = e;     // strict > : ties -> lower idx (matches lax.top_k)
    int i1 = (i0 == 0) ? 1 : 0;
    #pragma unroll
    for (int e = 0; e < NE; ++e){ if (e == i0) continue; if (pe[e] > pe[i1]) i1 = e; }
    double w0 = pe[i0], w1v = pe[i1], wsum = w0 + w1v;
    top_i[2*n] = i0; top_i[2*n+1] = i1;
    top_w[2*n] = (float)(w0/wsum); top_w[2*n+1] = (float)(w1v/wsum);
    atomicAdd(&counts[i0], 1); atomicAdd(&counts[i1], 1);
  }
}

// ---------------- tiny scan: 8-entry exclusive prefix ----------------
__global__ void scan_kernel(const int* __restrict__ counts, int* __restrict__ offsets, int* __restrict__ cursor){
  if (threadIdx.x == 0){
    int s = 0;
    for (int e = 0; e < NE; ++e){ offsets[e] = s; cursor[e] = s; s += counts[e]; }
  }
}

// ---------------- scatter tokens into expert-grouped lists ----------------
__global__ __launch_bounds__(256) void scatter_kernel(
    const int* __restrict__ top_i, const float* __restrict__ top_w,
    int* __restrict__ cursor, int* __restrict__ g_tok, float* __restrict__ g_w){
  int n = blockIdx.x*256 + threadIdx.x;
  #pragma unroll
  for (int k = 0; k < 2; ++k){
    int e = top_i[2*n+k];
    int pos = atomicAdd(&cursor[e], 1);
    g_tok[pos] = n;
    g_w[pos] = top_w[2*n+k];
  }
}

// ---------------- weight transpose + fp32->bf16: in [R][S] -> out [S][R], per expert ----------------
template<int R, int S>
__global__ __launch_bounds__(256) void transpose_cvt(const float* __restrict__ in, unsigned short* __restrict__ outp){
  __shared__ float tile[64][65];
  int e = blockIdx.z;
  const float* ip = in + (size_t)e*R*S;
  unsigned short* op = outp + (size_t)e*R*S;
  int s0 = blockIdx.x*64, r0 = blockIdx.y*64;
  int tid = threadIdx.x;
  #pragma unroll
  for (int i = 0; i < 4; ++i){
    int lin = i*256 + tid;
    int rr = lin >> 4, c4 = lin & 15;
    float4 v = *(const float4*)(ip + (size_t)(r0+rr)*S + s0 + c4*4);
    tile[rr][c4*4+0] = v.x; tile[rr][c4*4+1] = v.y;
    tile[rr][c4*4+2] = v.z; tile[rr][c4*4+3] = v.w;
  }
  __syncthreads();
  #pragma unroll
  for (int i = 0; i < 4; ++i){
    int lin = i*256 + tid;
    int ss = lin >> 4, rq = lin & 15;
    us4 o;
    o.x = f2bf(tile[rq*4+0][ss]);
    o.y = f2bf(tile[rq*4+1][ss]);
    o.z = f2bf(tile[rq*4+2][ss]);
    o.w = f2bf(tile[rq*4+3][ss]);
    *(us4*)(op + (size_t)(s0+ss)*R + r0 + rq*4) = o;
  }
}

// ---------------- grouped GEMM, 8-phase 256x256, DERIVED-WAIT pipeline ----------------
// BK=64, 8 waves (2Mx4N, per-wave 128x64). K=1024/block = 16 tiles = 8 iters.
// LDS 128KB: buf b at b*65536; A at 0 (halves mh*16384), B at 32768 (halves nh*16384).
// Stage ring per iter (each = 2 global_load_lds_dwordx4/thread, 16KB):
//   S0 p0: buf1.Bh1(t1)   S1 p1: buf1.Ah1(t1)   S2 p2: buf0.Ah0(t0+2)  S3 p3: buf0.Bh0(t0+2)
//   S4 p4: buf0.Ah1(t0+2) S5 p5: buf0.Bh1(t0+2) S6 p6: buf1.Ah0(t1+2)  S7 p7: buf1.Bh0(t1+2)
// Read deps (ages): p0<-S2',S3'(6,5)  p1<-S5'(4)  p2<-S4'(6)  p4<-S6',S7'(6,5)  p5<-S0(5)  p6<-S1(5)
// Derived waits (loads, 2/group): vmcnt(6)@p0, vmcnt(8)@p3,p4,p5,p7 -> no forced load younger
// than ~3.5 phases; loads stay in flight across barriers (T4). Last iter: vmcnt(4)/(2)/(0).
// EPI 0: h = gelu(x @ w1t^T) bf16.  EPI 1: out[token] += w * (h @ w2t^T), fp32 atomics.
template<int EPI, int SPLITK>
__global__ __launch_bounds__(512, 2) void gemm8ph(
    const unsigned short* __restrict__ A_src,
    const unsigned short* __restrict__ B_src,
    unsigned short* __restrict__ h_out,
    float* __restrict__ outp,
    const int* __restrict__ g_tok,
    const float* __restrict__ g_w,
    const int* __restrict__ counts,
    const int* __restrict__ offsets,
    int NDIM, int KSTRIDE){
  __shared__ alignas(128) char lds[131072];

  int z = blockIdx.z;
  int e  = z / SPLITK;
  int kz = z % SPLITK;
  int n_e = counts[e];
  int m0 = blockIdx.y*256;
  if (m0 >= n_e) return;
  int n0 = blockIdx.x*256;
  int g_base = offsets[e];
  int kstart = kz*1024;

  int tid = threadIdx.x, l = tid & 63, w = tid >> 6;   // 8 waves
  int wr = w >> 2, wc = w & 3;                         // wave tile: rows wr*128, cols wc*64
  int lrow = l & 15, q = l >> 4;

  // staging precompute. kinds: 0=A_h0 1=B_h0 2=A_h1 3=B_h1; j=0,1 insts per half.
  // halfrow r = j*64 + w*8 + (l>>3); LDS linear dst = region + j*8192 + w*1024 + l*16
  // source chunk pre-swizzled: c = (l&7) ^ (r&7)  ->  LDS(r,c) = SRC(r, c^(r&7))
  const unsigned short* sp[4][2];
  uint32_t sd[4][2];
  #pragma unroll
  for (int kind = 0; kind < 4; ++kind){
    #pragma unroll
    for (int j = 0; j < 2; ++j){
      int r = j*64 + w*8 + (l >> 3);
      int h = kind >> 1;
      int c = (l & 7) ^ (r & 7);
      if ((kind & 1) == 0){   // A: half h = rows {wr*128 + h*64 .. +63}
        int trow = (r >> 6)*128 + h*64 + (r & 63);
        int rg = m0 + trow; if (rg > n_e-1) rg = n_e-1;   // clamp partial tile
        size_t arow = (EPI == 0) ? (size_t)g_tok[g_base + rg] : (size_t)(g_base + rg);
        sp[kind][j] = A_src + arow*(size_t)KSTRIDE + kstart + c*8;
        sd[kind][j] = h*16384u + (uint32_t)(j*8192 + w*1024 + l*16);
      } else {                // B: half h = rows {wc*64 + h*32 .. +31}
        int trow = (r >> 5)*64 + h*32 + (r & 31);
        sp[kind][j] = B_src + ((size_t)e*NDIM + n0 + trow)*(size_t)KSTRIDE + kstart + c*8;
        sd[kind][j] = 32768u + h*16384u + (uint32_t)(j*8192 + w*1024 + l*16);
      }
    }
  }

  auto STG = [&](int kind, int buf, int kt){
    #pragma unroll
    for (int j = 0; j < 2; ++j)
      __builtin_amdgcn_global_load_lds(
        (const __attribute__((address_space(1))) void*)(sp[kind][j] + kt*64),
        (__attribute__((address_space(3))) void*)&lds[sd[kind][j] + (uint32_t)buf*65536u], 16, 0, 0);
  };

  // fragment read offsets within half: byte = halfrow*128 + 16*(q ^ (lrow&7)); ks=1 -> ^64
  uint32_t aoff[2][4], boff[2][2];
  #pragma unroll
  for (int mh = 0; mh < 2; ++mh)
    #pragma unroll
    for (int mm = 0; mm < 4; ++mm)
      aoff[mh][mm] = mh*16384u + (uint32_t)((wr*64 + mm*16 + lrow)*128) + 16u*(q ^ (lrow & 7));
  #pragma unroll
  for (int nh = 0; nh < 2; ++nh)
    #pragma unroll
    for (int nn = 0; nn < 2; ++nn)
      boff[nh][nn] = 32768u + nh*16384u + (uint32_t)((wc*32 + nn*16 + lrow)*128) + 16u*(q ^ (lrow & 7));

  bf16x8 a[4][2], b[2][2][2];
  f32x4 acc[8][4] = {};

  auto RDA = [&](int mh, int buf){
    #pragma unroll
    for (int mm = 0; mm < 4; ++mm)
      #pragma unroll
      for (int ks = 0; ks < 2; ++ks)
        a[mm][ks] = *(const bf16x8*)&lds[(aoff[mh][mm] ^ (ks*64)) + (uint32_t)buf*65536u];
  };
  auto RDB = [&](int nh, int buf){
    #pragma unroll
    for (int nn = 0; nn < 2; ++nn)
      #pragma unroll
      for (int ks = 0; ks < 2; ++ks)
        b[nh][nn][ks] = *(const bf16x8*)&lds[(boff[nh][nn] ^ (ks*64)) + (uint32_t)buf*65536u];
  };
  auto MM = [&](int mh, int nh){
    __builtin_amdgcn_s_setprio(1);
    #pragma unroll
    for (int mm = 0; mm < 4; ++mm)
      #pragma unroll
      for (int nn = 0; nn < 2; ++nn)
        #pragma unroll
        for (int ks = 0; ks < 2; ++ks)
          acc[mh*4+mm][nh*2+nn] =
            __builtin_amdgcn_mfma_f32_16x16x32_bf16(a[mm][ks], b[nh][nn][ks], acc[mh*4+mm][nh*2+nn], 0, 0, 0);
    __builtin_amdgcn_s_setprio(0);
  };

  // prologue: G0..G5 = tile0 all 4 halves -> buf0, tile1 h0 (A,B) -> buf1; then land G0,G1
  STG(0,0,0); STG(1,0,0); STG(2,0,0); STG(3,0,0);
  STG(0,1,1); STG(1,1,1);
  VM8();
  BARR();

  auto iter = [&](int i, bool last){
    int t1 = 2*i + 1;
    // p0: reads buf0 h0 (t0); S0 = buf1.Bh1(t1)
    RDA(0,0); RDB(0,0); STG(3,1,t1);
    VM6();
    BARR(); MM(0,0); BARR();
    // p1: reads buf0 Bh1 (t0); S1 = buf1.Ah1(t1)
    RDB(1,0); STG(2,1,t1);
    BARR(); MM(0,1); BARR();
    // p2: reads buf0 Ah1 (t0); S2 = buf0.Ah0(t0+2)
    RDA(1,0); if (!last) STG(0,0,t1+1);
    BARR(); MM(1,0); BARR();
    // p3: S3 = buf0.Bh0(t0+2)
    if (!last){ STG(1,0,t1+1); VM8(); } else { VM4(); }
    BARR(); MM(1,1); BARR();
    // p4: reads buf1 h0 (t1); S4 = buf0.Ah1(t0+2)
    RDA(0,1); RDB(0,1); if (!last) STG(2,0,t1+1);
    if (!last){ VM8(); } else { VM2(); }
    BARR(); MM(0,0); BARR();
    // p5: reads buf1 Bh1 (t1); S5 = buf0.Bh1(t0+2)
    RDB(1,1); if (!last) STG(3,0,t1+1);
    if (!last){ VM8(); } else { VM0(); }
    BARR(); MM(0,1); BARR();
    // p6: reads buf1 Ah1 (t1); S6 = buf1.Ah0(t1+2)
    RDA(1,1); if (!last) STG(0,1,t1+2);
    BARR(); MM(1,0); BARR();
    // p7: S7 = buf1.Bh0(t1+2)
    if (!last){ STG(1,1,t1+2); VM8(); }
    BARR(); MM(1,1); BARR();
  };

  #pragma unroll 1
  for (int i = 0; i < 7; ++i) iter(i, false);
  iter(7, true);

  // C/D layout (verified m89): col = lane&15, row = (lane>>4)*4 + j
  if (EPI == 0){
    #pragma unroll
    for (int m = 0; m < 8; ++m){
      #pragma unroll
      for (int j = 0; j < 4; ++j){
        int r = m0 + wr*128 + m*16 + q*4 + j;
        if (r < n_e){
          unsigned short* hp = h_out + (size_t)(g_base + r)*NDIM + n0 + wc*64 + lrow;
          #pragma unroll
          for (int n = 0; n < 4; ++n){
            float v = acc[m][n][j];
            v = 0.5f*v*(1.0f + erff(v*0.70710678118654752f));   // exact GELU
            hp[n*16] = f2bf(v);
          }
        }
      }
    }
  } else {
    #pragma unroll
    for (int m = 0; m < 8; ++m){
      #pragma unroll
      for (int j = 0; j < 4; ++j){
        int r = m0 + wr*128 + m*16 + q*4 + j;
        if (r < n_e){
          int slot = g_base + r;
          int t = g_tok[slot];
          float wgt = g_w[slot];
          float* op = outp + (size_t)t*NDIM + n0 + wc*64 + lrow;
          #pragma unroll
          for (int n = 0; n < 4; ++n)
            atomicAdd(op + n*16, wgt*acc[m][n][j]);
        }
      }
    }
  }
}

extern "C" void kernel_launch(void* const* d_in, const int* in_sizes, int n_in,
                              void* d_out, int out_size, void* d_ws, size_t ws_size,
                              hipStream_t stream) {
  const float* x  = (const float*)d_in[0];
  const float* rw = (const float*)d_in[1];
  const float* w1 = (const float*)d_in[2];
  const float* w2 = (const float*)d_in[3];

  size_t off = 0;
  auto alloc = [&](size_t sz) -> char* {
    char* p = (char*)d_ws + off;
    off += (sz + 255) & ~(size_t)255;
    return p;
  };
  unsigned short* x_bf = (unsigned short*)alloc((size_t)NTOK*CD*2);   // 8.4 MB
  unsigned short* w1t  = (unsigned short*)alloc((size_t)NE*CD*HD*2);  // 67 MB  [E][H][C]
  unsigned short* w2t  = (unsigned short*)alloc((size_t)NE*CD*HD*2);  // 67 MB  [E][C][H]
  unsigned short* hbuf = (unsigned short*)alloc((size_t)NTOK*2*HD*2); // 67 MB  [slot][H]
  int*   top_i  = (int*)alloc(NTOK*2*4);
  float* top_w  = (float*)alloc(NTOK*2*4);
  int*   counts = (int*)alloc(64);
  int*   offs   = (int*)alloc(64);
  int*   cursor = (int*)alloc(64);
  int*   g_tok  = (int*)alloc(NTOK*2*4);
  float* g_w    = (float*)alloc(NTOK*2*4);
  (void)ws_size; (void)in_sizes; (void)n_in; (void)out_size;

  hipMemsetAsync(d_out, 0, (size_t)NTOK*CD*4, stream);
  hipMemsetAsync(counts, 0, 64, stream);

  router_kernel<<<dim3(NTOK/4), dim3(256), 0, stream>>>(x, rw, x_bf, top_i, top_w, counts);
  scan_kernel<<<dim3(1), dim3(64), 0, stream>>>(counts, offs, cursor);
  scatter_kernel<<<dim3(NTOK/256), dim3(256), 0, stream>>>(top_i, top_w, cursor, g_tok, g_w);

  transpose_cvt<CD, HD><<<dim3(HD/64, CD/64, NE), dim3(256), 0, stream>>>(w1, w1t);
  transpose_cvt<HD, CD><<<dim3(CD/64, HD/64, NE), dim3(256), 0, stream>>>(w2, w2t);

  // GEMM1: h = gelu(x @ w1t^T)   M=n_e (<=2048 covered), N=H (16 nblk), K=1024; ~512 useful blocks
  gemm8ph<0, 1><<<dim3(16, 8, NE), dim3(512), 0, stream>>>(
      x_bf, w1t, hbuf, (float*)nullptr, g_tok, g_w, counts, offs, HD, CD);
  // GEMM2: out += w * (h @ w2t^T)   M=n_e, N=C (4 nblk), K=4096 split-K x4; ~544 useful blocks
  gemm8ph<1, 4><<<dim3(4, 8, NE*4), dim3(512), 0, stream>>>(
      hbuf, w2t, (unsigned short*)nullptr, (float*)d_out, g_tok, g_w, counts, offs, CD, HD);
}

// Round 8
// 516.222 us; speedup vs baseline: 1.1881x; 1.1873x over previous
//
#include <hip/hip_runtime.h>
#include <hip/hip_bf16.h>
#include <stdint.h>

#define NTOK 4096   // B*T = 2*2048
#define CD   1024
#define HD   4096
#define NE   8

typedef __attribute__((ext_vector_type(8))) short bf16x8;
typedef __attribute__((ext_vector_type(4))) float f32x4;
typedef __attribute__((ext_vector_type(4))) unsigned short us4;

__device__ __forceinline__ unsigned short f2bf(float f){
  __hip_bfloat16 h = __float2bfloat16(f);
  return *reinterpret_cast<unsigned short*>(&h);
}

// ---------------- router: logits (fp64 accum), softmax, top-2, renorm; x -> bf16 ----------------
__global__ __launch_bounds__(256) void router_kernel(
    const float* __restrict__ x, const float* __restrict__ rw,
    unsigned short* __restrict__ x_bf, int* __restrict__ top_i,
    float* __restrict__ top_w, int* __restrict__ counts){
  __shared__ float rw_lds[NE*CD];
  int tid = threadIdx.x;
  for (int i = tid; i < NE*CD/4; i += 256)
    ((float4*)rw_lds)[i] = ((const float4*)rw)[i];
  __syncthreads();
  int l = tid & 63, w = tid >> 6;
  int n = blockIdx.x*4 + w;

  float4 xv[4];
  #pragma unroll
  for (int j = 0; j < 4; ++j)
    xv[j] = ((const float4*)(x + (size_t)n*CD))[l + j*64];

  #pragma unroll
  for (int j = 0; j < 4; ++j){
    us4 o; o.x = f2bf(xv[j].x); o.y = f2bf(xv[j].y); o.z = f2bf(xv[j].z); o.w = f2bf(xv[j].w);
    *(us4*)(x_bf + (size_t)n*CD + l*4 + j*256) = o;
  }

  double le[NE];
  #pragma unroll
  for (int e = 0; e < NE; ++e){
    double p = 0.0;
    #pragma unroll
    for (int j = 0; j < 4; ++j){
      float4 rv = ((const float4*)(rw_lds + e*CD))[l + j*64];
      p += (double)xv[j].x*rv.x + (double)xv[j].y*rv.y + (double)xv[j].z*rv.z + (double)xv[j].w*rv.w;
    }
    #pragma unroll
    for (int d = 32; d >= 1; d >>= 1) p += __shfl_xor(p, d);
    le[e] = p;
  }
  if (l == 0){
    double m = le[0];
    #pragma unroll
    for (int e = 1; e < NE; ++e) m = le[e] > m ? le[e] : m;
    double pe[NE];
    #pragma unroll
    for (int e = 0; e < NE; ++e) pe[e] = exp(le[e]-m);
    int i0 = 0;
    #pragma unroll
    for (int e = 1; e < NE; ++e) if (pe[e] > pe[i0]) i0 = e;     // strict > : ties -> lower idx (matches lax.top_k)
    int i1 = (i0 == 0) ? 1 : 0;
    #pragma unroll
    for (int e = 0; e < NE; ++e){ if (e == i0) continue; if (pe[e] > pe[i1]) i1 = e; }
    double w0 = pe[i0], w1v = pe[i1], wsum = w0 + w1v;
    top_i[2*n] = i0; top_i[2*n+1] = i1;
    top_w[2*n] = (float)(w0/wsum); top_w[2*n+1] = (float)(w1v/wsum);
    atomicAdd(&counts[i0], 1); atomicAdd(&counts[i1], 1);
  }
}

// ---------------- tiny scan: 8-entry exclusive prefix ----------------
__global__ void scan_kernel(const int* __restrict__ counts, int* __restrict__ offsets, int* __restrict__ cursor){
  if (threadIdx.x == 0){
    int s = 0;
    for (int e = 0; e < NE; ++e){ offsets[e] = s; cursor[e] = s; s += counts[e]; }
  }
}

// ---------------- scatter tokens into expert-grouped lists ----------------
__global__ __launch_bounds__(256) void scatter_kernel(
    const int* __restrict__ top_i, const float* __restrict__ top_w,
    int* __restrict__ cursor, int* __restrict__ g_tok, float* __restrict__ g_w){
  int n = blockIdx.x*256 + threadIdx.x;
  #pragma unroll
  for (int k = 0; k < 2; ++k){
    int e = top_i[2*n+k];
    int pos = atomicAdd(&cursor[e], 1);
    g_tok[pos] = n;
    g_w[pos] = top_w[2*n+k];
  }
}

// ---------------- weight transpose + fp32->bf16: in [R][S] -> out [S][R], per expert ----------------
template<int R, int S>
__global__ __launch_bounds__(256) void transpose_cvt(const float* __restrict__ in, unsigned short* __restrict__ outp){
  __shared__ float tile[64][65];
  int e = blockIdx.z;
  const float* ip = in + (size_t)e*R*S;
  unsigned short* op = outp + (size_t)e*R*S;
  int s0 = blockIdx.x*64, r0 = blockIdx.y*64;
  int tid = threadIdx.x;
  #pragma unroll
  for (int i = 0; i < 4; ++i){
    int lin = i*256 + tid;
    int rr = lin >> 4, c4 = lin & 15;
    float4 v = *(const float4*)(ip + (size_t)(r0+rr)*S + s0 + c4*4);
    tile[rr][c4*4+0] = v.x; tile[rr][c4*4+1] = v.y;
    tile[rr][c4*4+2] = v.z; tile[rr][c4*4+3] = v.w;
  }
  __syncthreads();
  #pragma unroll
  for (int i = 0; i < 4; ++i){
    int lin = i*256 + tid;
    int ss = lin >> 4, rq = lin & 15;
    us4 o;
    o.x = f2bf(tile[rq*4+0][ss]);
    o.y = f2bf(tile[rq*4+1][ss]);
    o.z = f2bf(tile[rq*4+2][ss]);
    o.w = f2bf(tile[rq*4+3][ss]);
    *(us4*)(op + (size_t)(s0+ss)*R + r0 + rq*4) = o;
  }
}

// ---------------- grouped GEMM, 2-phase double-buffered, LINEAR LDS (m97 addressing) ----------------
// 128x128 tile, BK=64, 4 waves (2x2, per-wave 64x64), 64KB LDS dbuf -> 2 blocks/CU.
// Staging is PERFECTLY COALESCED: lane l -> row l>>3, 16B chunk l&7 (ascending within each
// 128B row) -> linear LDS dest. No XOR swizzle anywhere: T2 is measured-null at 2ph
// (m228d/m230) and the 16B-granule source permutation fragments VMEM sector coalescing.
// LDS bank conflicts on ds_read are accepted (m97/m98: 874 TF dense with 1.7e7 conflicts).
// EPI 0: h = gelu(x @ w1t^T) stored bf16 per-slot.  EPI 1: out[token] += w * (h @ w2t^T), fp32 atomics.
template<int KDIM, int EPI>
__global__ __launch_bounds__(256, 2) void gemm2ph(
    const unsigned short* __restrict__ A_src,
    const unsigned short* __restrict__ B_src,
    unsigned short* __restrict__ h_out,
    float* __restrict__ outp,
    const int* __restrict__ g_tok,
    const float* __restrict__ g_w,
    const int* __restrict__ counts,
    const int* __restrict__ offsets,
    int NDIM){
  constexpr int NT = KDIM/64;
  __shared__ alignas(128) char lds[65536];   // buf b at b*32768: A [0,16K) B [16K,32K)

  int e = blockIdx.z;
  int n_e = counts[e];
  int m0 = blockIdx.y*128;
  if (m0 >= n_e) return;
  int n0 = blockIdx.x*128;
  int g_base = offsets[e];

  int tid = threadIdx.x, l = tid & 63, w = tid >> 6;
  int wr = w >> 1, wc = w & 1;
  int lrow = l & 15, q = l >> 4;

  // staging: 32 segments (16 A + 16 B) of 8 rows x 128B; each wave owns 8.
  // LINEAR: lane l covers row (l>>3), chunk (l&7) -- ascending addresses, full coalescing.
  const unsigned short* src[8];
  uint32_t dst[8];
  #pragma unroll
  for (int i = 0; i < 8; ++i){
    int s = w*8 + i;                    // 0..31
    bool isA = s < 16;
    int srow = (s & 15)*8 + (l >> 3);
    int chunk = l & 7;
    if (isA){
      int rg = m0 + srow; if (rg > n_e-1) rg = n_e-1;   // clamp partial tile (rows discarded at epilogue)
      size_t arow;
      if (EPI == 0) arow = (size_t)g_tok[g_base + rg];  // gather token rows of x
      else          arow = (size_t)(g_base + rg);       // dense slot rows of h
      src[i] = A_src + arow*(size_t)KDIM + chunk*8;
    } else {
      src[i] = B_src + ((size_t)e*NDIM + n0 + srow)*(size_t)KDIM + chunk*8;
    }
    dst[i] = (isA ? 0u : 16384u) + (uint32_t)(s & 15)*1024u;
  }

  // fragment read offsets (LINEAR): byte = row*128 + q*16; ks=1 adds 64
  uint32_t a_off[4], b_off[4];
  #pragma unroll
  for (int m = 0; m < 4; ++m){
    int ra = wr*64 + m*16 + lrow;
    a_off[m] = ra*128 + q*16;
    int rb = wc*64 + m*16 + lrow;
    b_off[m] = 16384u + rb*128 + q*16;
  }

  f32x4 acc[4][4] = {};

  // prologue: stage K-tile 0 into buf 0
  #pragma unroll
  for (int i = 0; i < 8; ++i){
    __builtin_amdgcn_global_load_lds((const __attribute__((address_space(1))) void*)src[i],
                                     (__attribute__((address_space(3))) void*)&lds[dst[i]], 16, 0, 0);
    src[i] += 64;
  }
  __syncthreads();

  uint32_t buf = 0;
  for (int kt = 0; kt < NT; ++kt){
    if (kt + 1 < NT){
      uint32_t nb = (buf ^ 1)*32768u;
      #pragma unroll
      for (int i = 0; i < 8; ++i){
        __builtin_amdgcn_global_load_lds((const __attribute__((address_space(1))) void*)src[i],
                                         (__attribute__((address_space(3))) void*)&lds[dst[i] + nb], 16, 0, 0);
        src[i] += 64;
      }
    }
    uint32_t ro = buf*32768u;
    #pragma unroll
    for (int ks = 0; ks < 2; ++ks){
      bf16x8 av[4], bv[4];
      #pragma unroll
      for (int m = 0; m < 4; ++m){
        av[m] = *(const bf16x8*)&lds[a_off[m] + ks*64 + ro];
        bv[m] = *(const bf16x8*)&lds[b_off[m] + ks*64 + ro];
      }
      __builtin_amdgcn_s_setprio(1);
      #pragma unroll
      for (int m = 0; m < 4; ++m)
        #pragma unroll
        for (int n = 0; n < 4; ++n)
          acc[m][n] = __builtin_amdgcn_mfma_f32_16x16x32_bf16(av[m], bv[n], acc[m][n], 0, 0, 0);
      __builtin_amdgcn_s_setprio(0);
    }
    __syncthreads();   // drains vmcnt (prefetch done) + lgkmcnt; buf^1 ready, buf free
    buf ^= 1;
  }

  // C/D layout (verified m89): col = lane&15, row = (lane>>4)*4 + j
  if (EPI == 0){
    #pragma unroll
    for (int m = 0; m < 4; ++m){
      #pragma unroll
      for (int j = 0; j < 4; ++j){
        int r = m0 + wr*64 + m*16 + q*4 + j;
        if (r < n_e){
          unsigned short* hp = h_out + (size_t)(g_base + r)*NDIM + n0 + wc*64 + lrow;
          #pragma unroll
          for (int n = 0; n < 4; ++n){
            float v = acc[m][n][j];
            v = 0.5f*v*(1.0f + erff(v*0.70710678118654752f));   // exact GELU
            hp[n*16] = f2bf(v);
          }
        }
      }
    }
  } else {
    #pragma unroll
    for (int m = 0; m < 4; ++m){
      #pragma unroll
      for (int j = 0; j < 4; ++j){
        int r = m0 + wr*64 + m*16 + q*4 + j;
        if (r < n_e){
          int slot = g_base + r;
          int t = g_tok[slot];
          float wgt = g_w[slot];
          float* op = outp + (size_t)t*NDIM + n0 + wc*64 + lrow;
          #pragma unroll
          for (int n = 0; n < 4; ++n)
            atomicAdd(op + n*16, wgt*acc[m][n][j]);
        }
      }
    }
  }
}

extern "C" void kernel_launch(void* const* d_in, const int* in_sizes, int n_in,
                              void* d_out, int out_size, void* d_ws, size_t ws_size,
                              hipStream_t stream) {
  const float* x  = (const float*)d_in[0];
  const float* rw = (const float*)d_in[1];
  const float* w1 = (const float*)d_in[2];
  const float* w2 = (const float*)d_in[3];

  size_t off = 0;
  auto alloc = [&](size_t sz) -> char* {
    char* p = (char*)d_ws + off;
    off += (sz + 255) & ~(size_t)255;
    return p;
  };
  unsigned short* x_bf = (unsigned short*)alloc((size_t)NTOK*CD*2);   // 8.4 MB
  unsigned short* w1t  = (unsigned short*)alloc((size_t)NE*CD*HD*2);  // 67 MB  [E][H][C]
  unsigned short* w2t  = (unsigned short*)alloc((size_t)NE*CD*HD*2);  // 67 MB  [E][C][H]
  unsigned short* hbuf = (unsigned short*)alloc((size_t)NTOK*2*HD*2); // 67 MB  [slot][H]
  int*   top_i  = (int*)alloc(NTOK*2*4);
  float* top_w  = (float*)alloc(NTOK*2*4);
  int*   counts = (int*)alloc(64);
  int*   offs   = (int*)alloc(64);
  int*   cursor = (int*)alloc(64);
  int*   g_tok  = (int*)alloc(NTOK*2*4);
  float* g_w    = (float*)alloc(NTOK*2*4);
  (void)ws_size; (void)in_sizes; (void)n_in; (void)out_size;

  hipMemsetAsync(d_out, 0, (size_t)NTOK*CD*4, stream);
  hipMemsetAsync(counts, 0, 64, stream);

  router_kernel<<<dim3(NTOK/4), dim3(256), 0, stream>>>(x, rw, x_bf, top_i, top_w, counts);
  scan_kernel<<<dim3(1), dim3(64), 0, stream>>>(counts, offs, cursor);
  scatter_kernel<<<dim3(NTOK/256), dim3(256), 0, stream>>>(top_i, top_w, cursor, g_tok, g_w);

  transpose_cvt<CD, HD><<<dim3(HD/64, CD/64, NE), dim3(256), 0, stream>>>(w1, w1t);
  transpose_cvt<HD, CD><<<dim3(CD/64, HD/64, NE), dim3(256), 0, stream>>>(w2, w2t);

  // GEMM1: h = gelu(x @ w1t^T)   M=n_e, N=H (4096), K=C (1024)
  gemm2ph<CD, 0><<<dim3(HD/128, 32, NE), dim3(256), 0, stream>>>(
      x_bf, w1t, hbuf, (float*)nullptr, g_tok, g_w, counts, offs, HD);
  // GEMM2: out[token] += w * (h @ w2t^T)   M=n_e, N=C (1024), K=H (4096)
  gemm2ph<HD, 1><<<dim3(CD/128, 32, NE), dim3(256), 0, stream>>>(
      hbuf, w2t, (unsigned short*)nullptr, (float*)d_out, g_tok, g_w, counts, offs, CD);
}

// Round 9
// 481.719 us; speedup vs baseline: 1.2732x; 1.0716x over previous
//
#include <hip/hip_runtime.h>
#include <hip/hip_bf16.h>
#include <stdint.h>

#define NTOK 4096   // B*T = 2*2048
#define CD   1024
#define HD   4096
#define NE   8

typedef __attribute__((ext_vector_type(8))) short bf16x8;
typedef __attribute__((ext_vector_type(4))) float f32x4;
typedef __attribute__((ext_vector_type(4))) unsigned short us4;

__device__ __forceinline__ unsigned short f2bf(float f){
  __hip_bfloat16 h = __float2bfloat16(f);
  return *reinterpret_cast<unsigned short*>(&h);
}

// ---------------- router: logits (fp64 accum), softmax, top-2, renorm; x -> bf16 ----------------
__global__ __launch_bounds__(256) void router_kernel(
    const float* __restrict__ x, const float* __restrict__ rw,
    unsigned short* __restrict__ x_bf, int* __restrict__ top_i,
    float* __restrict__ top_w, int* __restrict__ counts){
  __shared__ float rw_lds[NE*CD];
  int tid = threadIdx.x;
  for (int i = tid; i < NE*CD/4; i += 256)
    ((float4*)rw_lds)[i] = ((const float4*)rw)[i];
  __syncthreads();
  int l = tid & 63, w = tid >> 6;
  int n = blockIdx.x*4 + w;

  float4 xv[4];
  #pragma unroll
  for (int j = 0; j < 4; ++j)
    xv[j] = ((const float4*)(x + (size_t)n*CD))[l + j*64];

  #pragma unroll
  for (int j = 0; j < 4; ++j){
    us4 o; o.x = f2bf(xv[j].x); o.y = f2bf(xv[j].y); o.z = f2bf(xv[j].z); o.w = f2bf(xv[j].w);
    *(us4*)(x_bf + (size_t)n*CD + l*4 + j*256) = o;
  }

  double le[NE];
  #pragma unroll
  for (int e = 0; e < NE; ++e){
    double p = 0.0;
    #pragma unroll
    for (int j = 0; j < 4; ++j){
      float4 rv = ((const float4*)(rw_lds + e*CD))[l + j*64];
      p += (double)xv[j].x*rv.x + (double)xv[j].y*rv.y + (double)xv[j].z*rv.z + (double)xv[j].w*rv.w;
    }
    #pragma unroll
    for (int d = 32; d >= 1; d >>= 1) p += __shfl_xor(p, d);
    le[e] = p;
  }
  if (l == 0){
    double m = le[0];
    #pragma unroll
    for (int e = 1; e < NE; ++e) m = le[e] > m ? le[e] : m;
    double pe[NE];
    #pragma unroll
    for (int e = 0; e < NE; ++e) pe[e] = exp(le[e]-m);
    int i0 = 0;
    #pragma unroll
    for (int e = 1; e < NE; ++e) if (pe[e] > pe[i0]) i0 = e;     // strict > : ties -> lower idx (matches lax.top_k)
    int i1 = (i0 == 0) ? 1 : 0;
    #pragma unroll
    for (int e = 0; e < NE; ++e){ if (e == i0) continue; if (pe[e] > pe[i1]) i1 = e; }
    double w0 = pe[i0], w1v = pe[i1], wsum = w0 + w1v;
    top_i[2*n] = i0; top_i[2*n+1] = i1;
    top_w[2*n] = (float)(w0/wsum); top_w[2*n+1] = (float)(w1v/wsum);
    atomicAdd(&counts[i0], 1); atomicAdd(&counts[i1], 1);
  }
}

// ---------------- tiny scan: 8-entry exclusive prefix ----------------
__global__ void scan_kernel(const int* __restrict__ counts, int* __restrict__ offsets, int* __restrict__ cursor){
  if (threadIdx.x == 0){
    int s = 0;
    for (int e = 0; e < NE; ++e){ offsets[e] = s; cursor[e] = s; s += counts[e]; }
  }
}

// ---------------- scatter tokens into expert-grouped lists ----------------
__global__ __launch_bounds__(256) void scatter_kernel(
    const int* __restrict__ top_i, const float* __restrict__ top_w,
    int* __restrict__ cursor, int* __restrict__ g_tok, float* __restrict__ g_w){
  int n = blockIdx.x*256 + threadIdx.x;
  #pragma unroll
  for (int k = 0; k < 2; ++k){
    int e = top_i[2*n+k];
    int pos = atomicAdd(&cursor[e], 1);
    g_tok[pos] = n;
    g_w[pos] = top_w[2*n+k];
  }
}

// ---------------- weight transpose + fp32->bf16: in [R][S] -> out [S][R], per expert ----------------
template<int R, int S>
__global__ __launch_bounds__(256) void transpose_cvt(const float* __restrict__ in, unsigned short* __restrict__ outp){
  __shared__ float tile[64][65];
  int e = blockIdx.z;
  const float* ip = in + (size_t)e*R*S;
  unsigned short* op = outp + (size_t)e*R*S;
  int s0 = blockIdx.x*64, r0 = blockIdx.y*64;
  int tid = threadIdx.x;
  #pragma unroll
  for (int i = 0; i < 4; ++i){
    int lin = i*256 + tid;
    int rr = lin >> 4, c4 = lin & 15;
    float4 v = *(const float4*)(ip + (size_t)(r0+rr)*S + s0 + c4*4);
    tile[rr][c4*4+0] = v.x; tile[rr][c4*4+1] = v.y;
    tile[rr][c4*4+2] = v.z; tile[rr][c4*4+3] = v.w;
  }
  __syncthreads();
  #pragma unroll
  for (int i = 0; i < 4; ++i){
    int lin = i*256 + tid;
    int ss = lin >> 4, rq = lin & 15;
    us4 o;
    o.x = f2bf(tile[rq*4+0][ss]);
    o.y = f2bf(tile[rq*4+1][ss]);
    o.z = f2bf(tile[rq*4+2][ss]);
    o.w = f2bf(tile[rq*4+3][ss]);
    *(us4*)(op + (size_t)(s0+ss)*R + r0 + rq*4) = o;
  }
}

// ---------------- grouped GEMM, HIGH-OCCUPANCY 2ph: 128x128 tile, BK=32, 4 waves ----------------
// LDS 32KB (dbuf of 16KB: A [0,8K) B [8K,16K)) -> 4+ blocks/CU (16 waves/CU vs previous 8).
// Independent blocks on a CU overlap each other's barrier/vmcnt stalls (m114 wave-level overlap)
// -- the session-wide bottleneck was 2 waves/SIMD with nothing to switch to.
// Staging: 4 gload_lds/thread; inst i, wave w, lane l -> chunk g=i*256+w*64+l of [A(512)|B(512)]
// 16B chunks; row=gg>>2, c=gg&3, source swizzled cs=c^(row&3), LDS dst linear g*16.
// ds_read: byte = row*64 + 16*(q^(row&3)) -> matches staged layout.
// EPI 0: h = gelu(x @ w1t^T) bf16.  EPI 1: out[token] += w * (h @ w2t^T), fp32 atomics (split-K safe).
template<int KLEN, int SPLITK, int EPI>
__global__ __launch_bounds__(256, 4) void gemm2ph(
    const unsigned short* __restrict__ A_src,
    const unsigned short* __restrict__ B_src,
    unsigned short* __restrict__ h_out,
    float* __restrict__ outp,
    const int* __restrict__ g_tok,
    const float* __restrict__ g_w,
    const int* __restrict__ counts,
    const int* __restrict__ offsets,
    int NDIM, int KSTRIDE){
  constexpr int NT = KLEN/32;
  __shared__ alignas(128) char lds[32768];   // buf b at b*16384

  int z = blockIdx.z;
  int e  = (SPLITK == 1) ? z : (z / SPLITK);
  int kz = (SPLITK == 1) ? 0 : (z % SPLITK);
  int n_e = counts[e];
  int m0 = blockIdx.y*128;
  if (m0 >= n_e) return;
  int n0 = blockIdx.x*128;
  int g_base = offsets[e];
  int kstart = kz*KLEN;

  int tid = threadIdx.x, l = tid & 63, w = tid >> 6;
  int wr = w >> 1, wc = w & 1;
  int lrow = l & 15, q = l >> 4;

  // staging pointers: 4 insts/thread cover A (8KB) then B (8KB)
  const unsigned short* src[4];
  uint32_t dst[4];
  #pragma unroll
  for (int i = 0; i < 4; ++i){
    int g = i*256 + w*64 + l;            // 0..1023
    bool isA = g < 512;
    int gg = isA ? g : (g - 512);
    int row = gg >> 2, c = gg & 3;
    int cs = c ^ (row & 3);              // source swizzle; LDS stays linear
    if (isA){
      int rg = m0 + row; if (rg > n_e-1) rg = n_e-1;   // clamp partial tile (rows discarded at epilogue)
      size_t arow;
      if (EPI == 0) arow = (size_t)g_tok[g_base + rg];  // gather token rows of x
      else          arow = (size_t)(g_base + rg);       // dense slot rows of h
      src[i] = A_src + arow*(size_t)KSTRIDE + kstart + cs*8;
    } else {
      src[i] = B_src + ((size_t)e*NDIM + n0 + row)*(size_t)KSTRIDE + kstart + cs*8;
    }
    dst[i] = (uint32_t)g*16u;
  }

  // fragment read offsets (swizzled): byte = row*64 + 16*(q ^ (row&3)) (+8192 for B)
  uint32_t a_off[4], b_off[4];
  #pragma unroll
  for (int m = 0; m < 4; ++m){
    int ra = wr*64 + m*16 + lrow;
    a_off[m] = (uint32_t)(ra*64) + 16u*(q ^ (ra & 3));
    int rb = wc*64 + m*16 + lrow;
    b_off[m] = 8192u + (uint32_t)(rb*64) + 16u*(q ^ (rb & 3));
  }

  f32x4 acc[4][4] = {};

  // prologue: stage K-tile 0 into buf 0
  #pragma unroll
  for (int i = 0; i < 4; ++i){
    __builtin_amdgcn_global_load_lds((const __attribute__((address_space(1))) void*)src[i],
                                     (__attribute__((address_space(3))) void*)&lds[dst[i]], 16, 0, 0);
    src[i] += 32;
  }
  __syncthreads();

  uint32_t buf = 0;
  #pragma unroll 1
  for (int kt = 0; kt < NT; ++kt){
    if (kt + 1 < NT){
      uint32_t nb = (buf ^ 1)*16384u;
      #pragma unroll
      for (int i = 0; i < 4; ++i){
        __builtin_amdgcn_global_load_lds((const __attribute__((address_space(1))) void*)src[i],
                                         (__attribute__((address_space(3))) void*)&lds[dst[i] + nb], 16, 0, 0);
        src[i] += 32;
      }
    }
    uint32_t ro = buf*16384u;
    bf16x8 av[4], bv[4];
    #pragma unroll
    for (int m = 0; m < 4; ++m){
      av[m] = *(const bf16x8*)&lds[a_off[m] + ro];
      bv[m] = *(const bf16x8*)&lds[b_off[m] + ro];
    }
    __builtin_amdgcn_s_setprio(1);
    #pragma unroll
    for (int m = 0; m < 4; ++m)
      #pragma unroll
      for (int n = 0; n < 4; ++n)
        acc[m][n] = __builtin_amdgcn_mfma_f32_16x16x32_bf16(av[m], bv[n], acc[m][n], 0, 0, 0);
    __builtin_amdgcn_s_setprio(0);
    __syncthreads();   // drains vmcnt (prefetch done) + lgkmcnt; buf^1 ready, buf free
    buf ^= 1;
  }

  // C/D layout (verified m89): col = lane&15, row = (lane>>4)*4 + j
  if (EPI == 0){
    #pragma unroll
    for (int m = 0; m < 4; ++m){
      #pragma unroll
      for (int j = 0; j < 4; ++j){
        int r = m0 + wr*64 + m*16 + q*4 + j;
        if (r < n_e){
          unsigned short* hp = h_out + (size_t)(g_base + r)*NDIM + n0 + wc*64 + lrow;
          #pragma unroll
          for (int n = 0; n < 4; ++n){
            float v = acc[m][n][j];
            v = 0.5f*v*(1.0f + erff(v*0.70710678118654752f));   // exact GELU
            hp[n*16] = f2bf(v);
          }
        }
      }
    }
  } else {
    #pragma unroll
    for (int m = 0; m < 4; ++m){
      #pragma unroll
      for (int j = 0; j < 4; ++j){
        int r = m0 + wr*64 + m*16 + q*4 + j;
        if (r < n_e){
          int slot = g_base + r;
          int t = g_tok[slot];
          float wgt = g_w[slot];
          float* op = outp + (size_t)t*NDIM + n0 + wc*64 + lrow;
          #pragma unroll
          for (int n = 0; n < 4; ++n)
            atomicAdd(op + n*16, wgt*acc[m][n][j]);
        }
      }
    }
  }
}

extern "C" void kernel_launch(void* const* d_in, const int* in_sizes, int n_in,
                              void* d_out, int out_size, void* d_ws, size_t ws_size,
                              hipStream_t stream) {
  const float* x  = (const float*)d_in[0];
  const float* rw = (const float*)d_in[1];
  const float* w1 = (const float*)d_in[2];
  const float* w2 = (const float*)d_in[3];

  size_t off = 0;
  auto alloc = [&](size_t sz) -> char* {
    char* p = (char*)d_ws + off;
    off += (sz + 255) & ~(size_t)255;
    return p;
  };
  unsigned short* x_bf = (unsigned short*)alloc((size_t)NTOK*CD*2);   // 8.4 MB
  unsigned short* w1t  = (unsigned short*)alloc((size_t)NE*CD*HD*2);  // 67 MB  [E][H][C]
  unsigned short* w2t  = (unsigned short*)alloc((size_t)NE*CD*HD*2);  // 67 MB  [E][C][H]
  unsigned short* hbuf = (unsigned short*)alloc((size_t)NTOK*2*HD*2); // 67 MB  [slot][H]
  int*   top_i  = (int*)alloc(NTOK*2*4);
  float* top_w  = (float*)alloc(NTOK*2*4);
  int*   counts = (int*)alloc(64);
  int*   offs   = (int*)alloc(64);
  int*   cursor = (int*)alloc(64);
  int*   g_tok  = (int*)alloc(NTOK*2*4);
  float* g_w    = (float*)alloc(NTOK*2*4);
  (void)ws_size; (void)in_sizes; (void)n_in; (void)out_size;

  hipMemsetAsync(d_out, 0, (size_t)NTOK*CD*4, stream);
  hipMemsetAsync(counts, 0, 64, stream);

  router_kernel<<<dim3(NTOK/4), dim3(256), 0, stream>>>(x, rw, x_bf, top_i, top_w, counts);
  scan_kernel<<<dim3(1), dim3(64), 0, stream>>>(counts, offs, cursor);
  scatter_kernel<<<dim3(NTOK/256), dim3(256), 0, stream>>>(top_i, top_w, cursor, g_tok, g_w);

  transpose_cvt<CD, HD><<<dim3(HD/64, CD/64, NE), dim3(256), 0, stream>>>(w1, w1t);
  transpose_cvt<HD, CD><<<dim3(CD/64, HD/64, NE), dim3(256), 0, stream>>>(w2, w2t);

  // GEMM1: h = gelu(x @ w1t^T)   M=n_e, N=H (4096), K=1024; ~2048 useful blocks, 4/CU
  gemm2ph<CD, 1, 0><<<dim3(HD/128, 16, NE), dim3(256), 0, stream>>>(
      x_bf, w1t, hbuf, (float*)nullptr, g_tok, g_w, counts, offs, HD, CD);
  // GEMM2: out[token] += w * (h @ w2t^T)   M=n_e, N=C (1024), K=4096 split-K x2; ~1024 useful blocks
  gemm2ph<HD/2, 2, 1><<<dim3(CD/128, 16, NE*2), dim3(256), 0, stream>>>(
      hbuf, w2t, (unsigned short*)nullptr, (float*)d_out, g_tok, g_w, counts, offs, CD, HD);
}